// Round 1
// baseline (466.348 us; speedup 1.0000x reference)
//
#include <hip/hip_runtime.h>
#include <hip/hip_bf16.h>
#include <math.h>

// ---------------------------------------------------------------------------
// GATv2 2-layer + linear head, MI355X (gfx950)
// GEMMs: single-term fp16 MFMA (C = A@W, fp32 accum), 128x128 tile, BK=32,
//   LDS double-buffer: global_load_lds stages tile k+1 while the MFMAs of
//   tile k run; explicit s_waitcnt(0) before each barrier forces the LDS-DMA
//   drain (defensive against compiler not modeling DMA->ds_read dependence).
// gat_node (this round): latency-bound fix on the round-9 kernel.
//   - grid-stride over nodes (2048 blocks): ~6 nodes/wave averages degree
//     imbalance (was: 1 node/wave, block retires on max of 4 Poisson(16)).
//   - depth-1 software pipeline: csr+xl gather for pair t+1 issued before
//     the compute of pair t, hiding the ~500cy L2/L3 gather latency.
//   - att setup hoisted out of the node loop; single csr_src[j+H] load per
//     half-wave instead of 2 loads + 2 readfirstlane.
//   Math per edge unchanged (packed-fp16 logits + fdot2, fp32 softmax/value
//   accum, no-max softmax: logits bounded ~+-2; shift cancels).
// CSR build: parallel 3-phase scan.
// ---------------------------------------------------------------------------

#define IN_DIM 256
#define HIDHC 256   // HEADS*HID
#define HID 64
#define OUT_DIM 40

using half8  = __attribute__((ext_vector_type(8))) _Float16;
using half4  = __attribute__((ext_vector_type(4))) _Float16;
using half2v = __attribute__((ext_vector_type(2))) _Float16;
using f32x4  = __attribute__((ext_vector_type(4))) float;

__device__ __forceinline__ void gload16(const void* g, void* l) {
    __builtin_amdgcn_global_load_lds(
        (const __attribute__((address_space(1))) void*)g,
        (__attribute__((address_space(3))) void*)l, 16, 0, 0);
}

// -------------------- CSR build --------------------

__global__ void edge_hist(const int* __restrict__ dst, int* __restrict__ deg, int E) {
    int i = blockIdx.x * blockDim.x + threadIdx.x;
    if (i < E) atomicAdd(&deg[dst[i]], 1);
}

__global__ void deg_block_reduce(const int* __restrict__ deg, int* __restrict__ bsum, int n) {
    int i = blockIdx.x * 256 + threadIdx.x;
    int v = (i < n) ? deg[i] : 0;
    #pragma unroll
    for (int off = 32; off; off >>= 1) v += __shfl_xor(v, off, 64);
    __shared__ int ws[4];
    int lane = threadIdx.x & 63, wid = threadIdx.x >> 6;
    if (lane == 0) ws[wid] = v;
    __syncthreads();
    if (threadIdx.x == 0) bsum[blockIdx.x] = ws[0] + ws[1] + ws[2] + ws[3];
}

__global__ void scan_bsums(const int* __restrict__ bsum, int* __restrict__ bpre, int nb) {
    __shared__ int s[256];
    int tid = threadIdx.x;
    int orig = (tid < nb) ? bsum[tid] : 0;
    s[tid] = orig;
    __syncthreads();
    #pragma unroll
    for (int off = 1; off < 256; off <<= 1) {
        int t = (tid >= off) ? s[tid - off] : 0;
        __syncthreads();
        s[tid] += t;
        __syncthreads();
    }
    if (tid < nb) bpre[tid] = s[tid] - orig;
}

__global__ void deg_scan_apply(const int* __restrict__ deg, const int* __restrict__ bpre,
                               int* __restrict__ offsets, int* __restrict__ cursor, int n) {
    int i = blockIdx.x * 256 + threadIdx.x;
    int lane = threadIdx.x & 63, wid = threadIdx.x >> 6;
    int v = (i < n) ? deg[i] : 0;
    int inc = v;
    #pragma unroll
    for (int off = 1; off < 64; off <<= 1) {
        int t = __shfl_up(inc, off, 64);
        if (lane >= off) inc += t;
    }
    __shared__ int ws[4];
    if (lane == 63) ws[wid] = inc;
    __syncthreads();
    int add = bpre[blockIdx.x];
    for (int w = 0; w < wid; ++w) add += ws[w];
    int incl = inc + add;
    if (i < n) { offsets[i + 1] = incl; cursor[i] = incl - v; }
    if (i == 0) offsets[0] = 0;
}

__global__ void edge_scatter(const int* __restrict__ src, const int* __restrict__ dst,
                             int* __restrict__ cursor, int* __restrict__ csr_src, int E) {
    int i = blockIdx.x * blockDim.x + threadIdx.x;
    if (i < E) {
        int p = atomicAdd(&cursor[dst[i]], 1);
        csr_src[p] = src[i];
    }
}

// -------------------- input prep --------------------

__global__ void cvt_f16(const float* __restrict__ in, _Float16* __restrict__ out, int n4) {
    int i = blockIdx.x * blockDim.x + threadIdx.x;
    if (i >= n4) return;
    float4 v = ((const float4*)in)[i];
    half4 h = { (_Float16)v.x, (_Float16)v.y, (_Float16)v.z, (_Float16)v.w };
    ((half4*)out)[i] = h;
}

// W [256][256] fp32 (k-major) -> per weight: [n][k] fp16 (transposed)
__global__ void prep_weights(const float* __restrict__ W0, const float* __restrict__ W1,
                             const float* __restrict__ W2, const float* __restrict__ W3,
                             _Float16* __restrict__ T) {
    const float* Wsel = (blockIdx.y == 0) ? W0 : (blockIdx.y == 1) ? W1
                      : (blockIdx.y == 2) ? W2 : W3;
    int k = blockIdx.x, nn = threadIdx.x;
    float v = Wsel[k * 256 + nn];
    T[(size_t)blockIdx.y * 65536 + (size_t)nn * 256 + k] = (_Float16)v;
}

// -------------------- MFMA GEMM (dual: blockIdx.z picks W/bias/C) --------------------
// C[M,256] = A[M,256] @ W + bias, fp16 in/out, fp32 accum.
// 128x128 tile, BK=32 (8 iters), LDS ping-pong via global_load_lds:
// stage kt+1 into buf^1 before the MFMAs of kt; explicit full waitcnt drain
// before each barrier guarantees DMA completion across the buffer swap.

__global__ __launch_bounds__(256) void gemm2_mfma(
    const _Float16* __restrict__ A,
    const _Float16* __restrict__ W0, const float* __restrict__ b0, _Float16* __restrict__ C0,
    const _Float16* __restrict__ W1, const float* __restrict__ b1, _Float16* __restrict__ C1,
    int M)
{
    __shared__ __align__(16) _Float16 sA[2][4096], sB[2][4096];   // 128x32 each buf

    const _Float16* W   = blockIdx.z ? W1 : W0;
    const float*    bias= blockIdx.z ? b1 : b0;
    _Float16*       C   = blockIdx.z ? C1 : C0;

    int tid = threadIdx.x;
    int bm = blockIdx.x * 128;
    int bn = blockIdx.y * 128;

    int lane = tid & 63, w = tid >> 6;
    int r = lane & 15, q = lane >> 4;
    int m0 = (w >> 1) * 64, n0 = (w & 1) * 64;

    // 2 granules per array per thread: g = tid + 256*i; kg = g>>7 (0..3), row = g&127
    int arow[2], brow[2], kgo[2], lds[2];
    #pragma unroll
    for (int i = 0; i < 2; ++i) {
        int g = tid + 256 * i;
        kgo[i] = (g >> 7) * 8;
        int row = g & 127;
        arow[i] = min(bm + row, M - 1);
        brow[i] = bn + row;
        lds[i] = g * 8;
    }

    f32x4 acc[4][4];
    #pragma unroll
    for (int i = 0; i < 4; ++i)
        #pragma unroll
        for (int j = 0; j < 4; ++j) acc[i][j] = (f32x4)0.f;

    // preload tile 0 into buffer 0
    #pragma unroll
    for (int i = 0; i < 2; ++i) {
        gload16(A + (size_t)arow[i] * 256 + kgo[i], &sA[0][lds[i]]);
        gload16(W + (size_t)brow[i] * 256 + kgo[i], &sB[0][lds[i]]);
    }
    __builtin_amdgcn_s_waitcnt(0);   // drain LDS-DMA
    __syncthreads();

    #pragma unroll 1
    for (int kt = 0; kt < 8; ++kt) {
        int buf = kt & 1;
        if (kt < 7) {
            int k0 = (kt + 1) * 32;
            #pragma unroll
            for (int i = 0; i < 2; ++i) {
                gload16(A + (size_t)arow[i] * 256 + k0 + kgo[i], &sA[buf ^ 1][lds[i]]);
                gload16(W + (size_t)brow[i] * 256 + k0 + kgo[i], &sB[buf ^ 1][lds[i]]);
            }
        }
        half8 a[4], b[4];
        #pragma unroll
        for (int i = 0; i < 4; ++i) {
            a[i] = *(const half8*)(&sA[buf][(q * 128 + m0 + i * 16 + r) * 8]);
            b[i] = *(const half8*)(&sB[buf][(q * 128 + n0 + i * 16 + r) * 8]);
        }
        #pragma unroll
        for (int i = 0; i < 4; ++i)
            #pragma unroll
            for (int j = 0; j < 4; ++j)
                acc[i][j] = __builtin_amdgcn_mfma_f32_16x16x32_f16(a[i], b[j], acc[i][j], 0, 0, 0);
        __builtin_amdgcn_s_waitcnt(0);   // drain prefetch DMA before buffer swap
        __syncthreads();
    }

    // epilogue: C/D layout col=lane&15, row=q*4+reg
    float bv[4];
    #pragma unroll
    for (int j = 0; j < 4; ++j) bv[j] = bias[bn + n0 + j * 16 + r];
    #pragma unroll
    for (int i = 0; i < 4; ++i) {
        #pragma unroll
        for (int reg = 0; reg < 4; ++reg) {
            int row = bm + m0 + i * 16 + q * 4 + reg;
            if (row < M) {
                #pragma unroll
                for (int j = 0; j < 4; ++j)
                    C[(size_t)row * 256 + bn + n0 + j * 16 + r] =
                        (_Float16)(acc[i][j][reg] + bv[j]);
            }
        }
    }
}

// -------------------- GAT node kernel: half-wave-per-edge, pipelined --------

__global__ __launch_bounds__(256) void gat_node(
    const _Float16* __restrict__ xl, const _Float16* __restrict__ xr,
    const float* __restrict__ att, const float* __restrict__ bias,
    const int* __restrict__ offsets, const int* __restrict__ csr_src,
    void* __restrict__ out0, int n, int mode)
{
    int wid = threadIdx.x >> 6;
    int lane = threadIdx.x & 63;
    int H = lane >> 5;
    int p = lane & 31;

    const half2v c02 = { (_Float16)0.2f, (_Float16)0.2f };

    // node-invariant: attention vector (per-lane 8 channels)
    float4 af0 = *(const float4*)(att + p * 8);
    float4 af1 = *(const float4*)(att + p * 8 + 4);
    half2v at01 = { (_Float16)af0.x, (_Float16)af0.y };
    half2v at23 = { (_Float16)af0.z, (_Float16)af0.w };
    half2v at45 = { (_Float16)af1.x, (_Float16)af1.y };
    half2v at67 = { (_Float16)af1.z, (_Float16)af1.w };

    const int stride = gridDim.x << 2;
    for (int node = (blockIdx.x << 2) + wid; node < n; node += stride) {

        half8 xrh = *(const half8*)(xr + (size_t)node * HIDHC + p * 8);
        half2v xr01 = __builtin_shufflevector(xrh, xrh, 0, 1);
        half2v xr23 = __builtin_shufflevector(xrh, xrh, 2, 3);
        half2v xr45 = __builtin_shufflevector(xrh, xrh, 4, 5);
        half2v xr67 = __builtin_shufflevector(xrh, xrh, 6, 7);

        float acc[8];
        #pragma unroll
        for (int k = 0; k < 8; ++k) acc[k] = 0.f;
        float d = 0.f;

        int j0 = __builtin_amdgcn_readfirstlane(offsets[node]);
        int j1 = __builtin_amdgcn_readfirstlane(offsets[node + 1]);
        int npairs = (j1 - j0) >> 1;

        int j = j0;
        half8 hn;                        // prefetched xl row for current pair
        if (npairs > 0) {
            int s = csr_src[j + H];      // uniform within half-wave
            hn = *(const half8*)(xl + (size_t)s * HIDHC + p * 8);
        }
        for (int t = 0; t < npairs; ++t) {
            half8 h = hn;
            j += 2;
            if (t + 1 < npairs) {        // issue next pair's gather before compute
                int s = csr_src[j + H];
                hn = *(const half8*)(xl + (size_t)s * HIDHC + p * 8);
            }
            half2v h01 = __builtin_shufflevector(h, h, 0, 1);
            half2v h23 = __builtin_shufflevector(h, h, 2, 3);
            half2v h45 = __builtin_shufflevector(h, h, 4, 5);
            half2v h67 = __builtin_shufflevector(h, h, 6, 7);
            half2v s01 = h01 + xr01, s23 = h23 + xr23, s45 = h45 + xr45, s67 = h67 + xr67;
            half2v l01 = __builtin_elementwise_max(s01, s01 * c02);
            half2v l23 = __builtin_elementwise_max(s23, s23 * c02);
            half2v l45 = __builtin_elementwise_max(s45, s45 * c02);
            half2v l67 = __builtin_elementwise_max(s67, s67 * c02);
            float e = __builtin_amdgcn_fdot2(l01, at01, 0.f, false);
            e = __builtin_amdgcn_fdot2(l23, at23, e, false);
            e = __builtin_amdgcn_fdot2(l45, at45, e, false);
            e = __builtin_amdgcn_fdot2(l67, at67, e, false);
            e += __shfl_xor(e, 1);
            e += __shfl_xor(e, 2);
            e += __shfl_xor(e, 4);
            float pw = __expf(e);
            d += pw;
            #pragma unroll
            for (int k = 0; k < 8; ++k) acc[k] = fmaf(pw, (float)h[k], acc[k]);
        }
        if (j < j1) {                    // odd leftover edge (H==0 half only)
            int s0 = csr_src[j];
            half8 h = *(const half8*)(xl + (size_t)s0 * HIDHC + p * 8);
            half2v h01 = __builtin_shufflevector(h, h, 0, 1);
            half2v h23 = __builtin_shufflevector(h, h, 2, 3);
            half2v h45 = __builtin_shufflevector(h, h, 4, 5);
            half2v h67 = __builtin_shufflevector(h, h, 6, 7);
            half2v s01 = h01 + xr01, s23 = h23 + xr23, s45 = h45 + xr45, s67 = h67 + xr67;
            half2v l01 = __builtin_elementwise_max(s01, s01 * c02);
            half2v l23 = __builtin_elementwise_max(s23, s23 * c02);
            half2v l45 = __builtin_elementwise_max(s45, s45 * c02);
            half2v l67 = __builtin_elementwise_max(s67, s67 * c02);
            float e = __builtin_amdgcn_fdot2(l01, at01, 0.f, false);
            e = __builtin_amdgcn_fdot2(l23, at23, e, false);
            e = __builtin_amdgcn_fdot2(l45, at45, e, false);
            e = __builtin_amdgcn_fdot2(l67, at67, e, false);
            e += __shfl_xor(e, 1);
            e += __shfl_xor(e, 2);
            e += __shfl_xor(e, 4);
            float pw = (H == 0) ? __expf(e) : 0.f;
            d += pw;
            #pragma unroll
            for (int k = 0; k < 8; ++k) acc[k] = fmaf(pw, (float)h[k], acc[k]);
        }

        d += __shfl_xor(d, 32);
        #pragma unroll
        for (int k = 0; k < 8; ++k) acc[k] += __shfl_xor(acc[k], 32);

        float inv = 1.f / (d + 1e-16f);
        float o[8];
        #pragma unroll
        for (int k = 0; k < 8; ++k) o[k] = acc[k] * inv;

        if (mode == 0) {
            if (H == 0) {
                float4 b0 = *(const float4*)(bias + p * 8);
                float4 b1 = *(const float4*)(bias + p * 8 + 4);
                float bb[8] = { b0.x, b0.y, b0.z, b0.w, b1.x, b1.y, b1.z, b1.w };
                half8 hh;
                #pragma unroll
                for (int k = 0; k < 8; ++k) hh[k] = (_Float16)fmaxf(o[k] + bb[k], 0.f);
                *(half8*)((_Float16*)out0 + (size_t)node * HIDHC + p * 8) = hh;
            }
        } else {
            #pragma unroll
            for (int k = 0; k < 8; ++k) {
                o[k] += __shfl_xor(o[k], 8);
                o[k] += __shfl_xor(o[k], 16);
            }
            if (lane < 8) {
                float4 b0 = *(const float4*)(bias + p * 8);
                float4 b1 = *(const float4*)(bias + p * 8 + 4);
                float bb[8] = { b0.x, b0.y, b0.z, b0.w, b1.x, b1.y, b1.z, b1.w };
                float4 o0, o1;
                o0.x = fmaxf(o[0] * 0.25f + bb[0], 0.f);
                o0.y = fmaxf(o[1] * 0.25f + bb[1], 0.f);
                o0.z = fmaxf(o[2] * 0.25f + bb[2], 0.f);
                o0.w = fmaxf(o[3] * 0.25f + bb[3], 0.f);
                o1.x = fmaxf(o[4] * 0.25f + bb[4], 0.f);
                o1.y = fmaxf(o[5] * 0.25f + bb[5], 0.f);
                o1.z = fmaxf(o[6] * 0.25f + bb[6], 0.f);
                o1.w = fmaxf(o[7] * 0.25f + bb[7], 0.f);
                float* dst = (float*)out0 + (size_t)node * HID + p * 8;
                *(float4*)dst = o0;
                *(float4*)(dst + 4) = o1;
            }
        }
    }
}

// -------------------- final linear: out[N,40] = h2[N,64] @ Wc[64,40] + bc --------------------

__global__ __launch_bounds__(256) void final_linear(
    const float* __restrict__ h2, const float* __restrict__ Wc,
    const float* __restrict__ bc, float* __restrict__ out, int n)
{
    __shared__ float Ws[HID * OUT_DIM];
    __shared__ float bs[OUT_DIM];
    __shared__ float hs[64][HID + 1];

    for (int i = threadIdx.x; i < HID * OUT_DIM; i += 256) Ws[i] = Wc[i];
    if (threadIdx.x < OUT_DIM) bs[threadIdx.x] = bc[threadIdx.x];

    int n0 = blockIdx.x * 64;
    for (int i = threadIdx.x; i < 64 * HID; i += 256) {
        int r = i >> 6, c = i & 63;
        int node = n0 + r;
        hs[r][c] = (node < n) ? h2[(size_t)node * HID + c] : 0.f;
    }
    __syncthreads();

    for (int idx = threadIdx.x; idx < 64 * OUT_DIM; idx += 256) {
        int r = idx / OUT_DIM, o = idx % OUT_DIM;
        int node = n0 + r;
        if (node < n) {
            float s = bs[o];
            #pragma unroll
            for (int c = 0; c < HID; ++c) s = fmaf(hs[r][c], Ws[c * OUT_DIM + o], s);
            out[(size_t)node * OUT_DIM + o] = s;
        }
    }
}

// -------------------- launch --------------------

extern "C" void kernel_launch(void* const* d_in, const int* in_sizes, int n_in,
                              void* d_out, int out_size, void* d_ws, size_t ws_size,
                              hipStream_t stream) {
    const int N = in_sizes[0] / IN_DIM;   // 50000
    const int E = in_sizes[1];            // 800000

    const float* x    = (const float*)d_in[0];
    const int*   src  = (const int*)d_in[1];
    const int*   dst  = (const int*)d_in[2];
    const float* Wl1  = (const float*)d_in[3];
    const float* bl1  = (const float*)d_in[4];
    const float* Wr1  = (const float*)d_in[5];
    const float* br1  = (const float*)d_in[6];
    const float* att1 = (const float*)d_in[7];
    const float* bias1= (const float*)d_in[8];
    const float* Wl2  = (const float*)d_in[9];
    const float* bl2  = (const float*)d_in[10];
    const float* Wr2  = (const float*)d_in[11];
    const float* br2  = (const float*)d_in[12];
    const float* att2 = (const float*)d_in[13];
    const float* bias2= (const float*)d_in[14];
    const float* Wc   = (const float*)d_in[15];
    const float* bc   = (const float*)d_in[16];

    char* ws = (char*)d_ws;
    size_t off = 0;
    _Float16* xlh = (_Float16*)(ws + off); off += (size_t)N * HIDHC * 2;  // xl fp16
    _Float16* xrh = (_Float16*)(ws + off); off += (size_t)N * HIDHC * 2;  // xr fp16
    _Float16* Af  = (_Float16*)(ws + off); off += (size_t)N * HIDHC * 2;  // x / h1 fp16
    float*    h2  = (float*)(ws + off);    off += (size_t)N * HID * 4;
    _Float16* Wt  = (_Float16*)(ws + off); off += (size_t)4 * 65536 * 2;
    int* deg     = (int*)(ws + off); off += (size_t)N * 4;
    int* offsets = (int*)(ws + off); off += (size_t)(N + 1) * 4;
    int* cursor  = (int*)(ws + off); off += (size_t)N * 4;
    int* csr     = (int*)(ws + off); off += (size_t)E * 4;
    int* bsum    = (int*)(ws + off); off += 256 * 4;
    int* bpre    = (int*)(ws + off); off += 256 * 4;

    const int NB = (N + 255) / 256;

    // CSR build (parallel scan) + input prep
    hipMemsetAsync(deg, 0, (size_t)N * 4, stream);
    edge_hist<<<(E + 255) / 256, 256, 0, stream>>>(dst, deg, E);
    deg_block_reduce<<<NB, 256, 0, stream>>>(deg, bsum, N);
    scan_bsums<<<1, 256, 0, stream>>>(bsum, bpre, NB);
    deg_scan_apply<<<NB, 256, 0, stream>>>(deg, bpre, offsets, cursor, N);
    edge_scatter<<<(E + 255) / 256, 256, 0, stream>>>(src, dst, cursor, csr, E);
    prep_weights<<<dim3(256, 4), 256, 0, stream>>>(Wl1, Wr1, Wl2, Wr2, Wt);
    cvt_f16<<<(N * HIDHC / 4 + 255) / 256, 256, 0, stream>>>(x, Af, N * HIDHC / 4);

    const int KW = 65536;
    dim3 gg((N + 127) / 128, 2, 2);
    int gb = (N + 3) / 4; if (gb > 2048) gb = 2048;   // grid-stride: ~6 nodes/wave
    // layer 1
    gemm2_mfma<<<gg, 256, 0, stream>>>(Af,
        Wt + 0 * KW, bl1, xlh,
        Wt + 1 * KW, br1, xrh, N);
    gat_node<<<gb, 256, 0, stream>>>(xlh, xrh, att1, bias1, offsets, csr,
                                     (void*)Af, N, 0);
    // layer 2
    gemm2_mfma<<<gg, 256, 0, stream>>>(Af,
        Wt + 2 * KW, bl2, xlh,
        Wt + 3 * KW, br2, xrh, N);
    gat_node<<<gb, 256, 0, stream>>>(xlh, xrh, att2, bias2, offsets, csr,
                                     (void*)h2, N, 1);
    // head
    final_linear<<<(N + 63) / 64, 256, 0, stream>>>(h2, Wc, bc, (float*)d_out, N);
}

// Round 2
// 464.610 us; speedup vs baseline: 1.0037x; 1.0037x over previous
//
#include <hip/hip_runtime.h>
#include <hip/hip_bf16.h>
#include <math.h>

// ---------------------------------------------------------------------------
// GATv2 2-layer + linear head, MI355X (gfx950)
// GEMMs: single-term fp16 MFMA (C = A@W, fp32 accum), 128x128 tile, BK=32,
//   LDS double-buffer via global_load_lds (unchanged from round 0).
// gat_node (this round): round-0 structure (1 node/wave, 12500 blocks,
//   dynamic balancing) + two latency fixes:
//   - adjacency row preloaded ONCE per node: idxv = csr_src[j0+lane]
//     (one coalesced load covers deg<=64 edges); per-pair source indices
//     come from __shfl (ds_bpermute) -> no csr load, and no load-address
//     dependence inside the loop.
//   - depth-2 rotating gather pipeline: two 512B xl-row gathers in flight
//     across two compute blocks (~200cy), hiding L2/L3 latency.
//   deg>64 falls back to the round-0 scalar-csr path (Poisson(16): ~never).
//   Math per edge unchanged (packed-fp16 logits + fdot2, fp32 softmax/value
//   accum, no-max softmax: logits bounded ~+-2; shift cancels).
// CSR build: parallel 3-phase scan.
// ---------------------------------------------------------------------------

#define IN_DIM 256
#define HIDHC 256   // HEADS*HID
#define HID 64
#define OUT_DIM 40

using half8  = __attribute__((ext_vector_type(8))) _Float16;
using half4  = __attribute__((ext_vector_type(4))) _Float16;
using half2v = __attribute__((ext_vector_type(2))) _Float16;
using f32x4  = __attribute__((ext_vector_type(4))) float;

__device__ __forceinline__ void gload16(const void* g, void* l) {
    __builtin_amdgcn_global_load_lds(
        (const __attribute__((address_space(1))) void*)g,
        (__attribute__((address_space(3))) void*)l, 16, 0, 0);
}

// -------------------- CSR build --------------------

__global__ void edge_hist(const int* __restrict__ dst, int* __restrict__ deg, int E) {
    int i = blockIdx.x * blockDim.x + threadIdx.x;
    if (i < E) atomicAdd(&deg[dst[i]], 1);
}

__global__ void deg_block_reduce(const int* __restrict__ deg, int* __restrict__ bsum, int n) {
    int i = blockIdx.x * 256 + threadIdx.x;
    int v = (i < n) ? deg[i] : 0;
    #pragma unroll
    for (int off = 32; off; off >>= 1) v += __shfl_xor(v, off, 64);
    __shared__ int ws[4];
    int lane = threadIdx.x & 63, wid = threadIdx.x >> 6;
    if (lane == 0) ws[wid] = v;
    __syncthreads();
    if (threadIdx.x == 0) bsum[blockIdx.x] = ws[0] + ws[1] + ws[2] + ws[3];
}

__global__ void scan_bsums(const int* __restrict__ bsum, int* __restrict__ bpre, int nb) {
    __shared__ int s[256];
    int tid = threadIdx.x;
    int orig = (tid < nb) ? bsum[tid] : 0;
    s[tid] = orig;
    __syncthreads();
    #pragma unroll
    for (int off = 1; off < 256; off <<= 1) {
        int t = (tid >= off) ? s[tid - off] : 0;
        __syncthreads();
        s[tid] += t;
        __syncthreads();
    }
    if (tid < nb) bpre[tid] = s[tid] - orig;
}

__global__ void deg_scan_apply(const int* __restrict__ deg, const int* __restrict__ bpre,
                               int* __restrict__ offsets, int* __restrict__ cursor, int n) {
    int i = blockIdx.x * 256 + threadIdx.x;
    int lane = threadIdx.x & 63, wid = threadIdx.x >> 6;
    int v = (i < n) ? deg[i] : 0;
    int inc = v;
    #pragma unroll
    for (int off = 1; off < 64; off <<= 1) {
        int t = __shfl_up(inc, off, 64);
        if (lane >= off) inc += t;
    }
    __shared__ int ws[4];
    if (lane == 63) ws[wid] = inc;
    __syncthreads();
    int add = bpre[blockIdx.x];
    for (int w = 0; w < wid; ++w) add += ws[w];
    int incl = inc + add;
    if (i < n) { offsets[i + 1] = incl; cursor[i] = incl - v; }
    if (i == 0) offsets[0] = 0;
}

__global__ void edge_scatter(const int* __restrict__ src, const int* __restrict__ dst,
                             int* __restrict__ cursor, int* __restrict__ csr_src, int E) {
    int i = blockIdx.x * blockDim.x + threadIdx.x;
    if (i < E) {
        int p = atomicAdd(&cursor[dst[i]], 1);
        csr_src[p] = src[i];
    }
}

// -------------------- input prep --------------------

__global__ void cvt_f16(const float* __restrict__ in, _Float16* __restrict__ out, int n4) {
    int i = blockIdx.x * blockDim.x + threadIdx.x;
    if (i >= n4) return;
    float4 v = ((const float4*)in)[i];
    half4 h = { (_Float16)v.x, (_Float16)v.y, (_Float16)v.z, (_Float16)v.w };
    ((half4*)out)[i] = h;
}

// W [256][256] fp32 (k-major) -> per weight: [n][k] fp16 (transposed)
__global__ void prep_weights(const float* __restrict__ W0, const float* __restrict__ W1,
                             const float* __restrict__ W2, const float* __restrict__ W3,
                             _Float16* __restrict__ T) {
    const float* Wsel = (blockIdx.y == 0) ? W0 : (blockIdx.y == 1) ? W1
                      : (blockIdx.y == 2) ? W2 : W3;
    int k = blockIdx.x, nn = threadIdx.x;
    float v = Wsel[k * 256 + nn];
    T[(size_t)blockIdx.y * 65536 + (size_t)nn * 256 + k] = (_Float16)v;
}

// -------------------- MFMA GEMM (dual: blockIdx.z picks W/bias/C) --------------------
// C[M,256] = A[M,256] @ W + bias, fp16 in/out, fp32 accum.
// 128x128 tile, BK=32 (8 iters), LDS ping-pong via global_load_lds:
// stage kt+1 into buf^1 before the MFMAs of kt; explicit full waitcnt drain
// before each barrier guarantees DMA completion across the buffer swap.

__global__ __launch_bounds__(256) void gemm2_mfma(
    const _Float16* __restrict__ A,
    const _Float16* __restrict__ W0, const float* __restrict__ b0, _Float16* __restrict__ C0,
    const _Float16* __restrict__ W1, const float* __restrict__ b1, _Float16* __restrict__ C1,
    int M)
{
    __shared__ __align__(16) _Float16 sA[2][4096], sB[2][4096];   // 128x32 each buf

    const _Float16* W   = blockIdx.z ? W1 : W0;
    const float*    bias= blockIdx.z ? b1 : b0;
    _Float16*       C   = blockIdx.z ? C1 : C0;

    int tid = threadIdx.x;
    int bm = blockIdx.x * 128;
    int bn = blockIdx.y * 128;

    int lane = tid & 63, w = tid >> 6;
    int r = lane & 15, q = lane >> 4;
    int m0 = (w >> 1) * 64, n0 = (w & 1) * 64;

    // 2 granules per array per thread: g = tid + 256*i; kg = g>>7 (0..3), row = g&127
    int arow[2], brow[2], kgo[2], lds[2];
    #pragma unroll
    for (int i = 0; i < 2; ++i) {
        int g = tid + 256 * i;
        kgo[i] = (g >> 7) * 8;
        int row = g & 127;
        arow[i] = min(bm + row, M - 1);
        brow[i] = bn + row;
        lds[i] = g * 8;
    }

    f32x4 acc[4][4];
    #pragma unroll
    for (int i = 0; i < 4; ++i)
        #pragma unroll
        for (int j = 0; j < 4; ++j) acc[i][j] = (f32x4)0.f;

    // preload tile 0 into buffer 0
    #pragma unroll
    for (int i = 0; i < 2; ++i) {
        gload16(A + (size_t)arow[i] * 256 + kgo[i], &sA[0][lds[i]]);
        gload16(W + (size_t)brow[i] * 256 + kgo[i], &sB[0][lds[i]]);
    }
    __builtin_amdgcn_s_waitcnt(0);   // drain LDS-DMA
    __syncthreads();

    #pragma unroll 1
    for (int kt = 0; kt < 8; ++kt) {
        int buf = kt & 1;
        if (kt < 7) {
            int k0 = (kt + 1) * 32;
            #pragma unroll
            for (int i = 0; i < 2; ++i) {
                gload16(A + (size_t)arow[i] * 256 + k0 + kgo[i], &sA[buf ^ 1][lds[i]]);
                gload16(W + (size_t)brow[i] * 256 + k0 + kgo[i], &sB[buf ^ 1][lds[i]]);
            }
        }
        half8 a[4], b[4];
        #pragma unroll
        for (int i = 0; i < 4; ++i) {
            a[i] = *(const half8*)(&sA[buf][(q * 128 + m0 + i * 16 + r) * 8]);
            b[i] = *(const half8*)(&sB[buf][(q * 128 + n0 + i * 16 + r) * 8]);
        }
        #pragma unroll
        for (int i = 0; i < 4; ++i)
            #pragma unroll
            for (int j = 0; j < 4; ++j)
                acc[i][j] = __builtin_amdgcn_mfma_f32_16x16x32_f16(a[i], b[j], acc[i][j], 0, 0, 0);
        __builtin_amdgcn_s_waitcnt(0);   // drain prefetch DMA before buffer swap
        __syncthreads();
    }

    // epilogue: C/D layout col=lane&15, row=q*4+reg
    float bv[4];
    #pragma unroll
    for (int j = 0; j < 4; ++j) bv[j] = bias[bn + n0 + j * 16 + r];
    #pragma unroll
    for (int i = 0; i < 4; ++i) {
        #pragma unroll
        for (int reg = 0; reg < 4; ++reg) {
            int row = bm + m0 + i * 16 + q * 4 + reg;
            if (row < M) {
                #pragma unroll
                for (int j = 0; j < 4; ++j)
                    C[(size_t)row * 256 + bn + n0 + j * 16 + r] =
                        (_Float16)(acc[i][j][reg] + bv[j]);
            }
        }
    }
}

// -------------------- GAT node kernel: half-wave-per-edge ---------------------
// 1 node/wave, 12500 blocks (dynamic balancing). Adjacency row preloaded into
// idxv (1 coalesced load, deg<=64); per-pair src via __shfl; depth-2 rotating
// gather pipeline keeps two 512B xl rows in flight. deg>64 -> scalar fallback.

__global__ __launch_bounds__(256) void gat_node(
    const _Float16* __restrict__ xl, const _Float16* __restrict__ xr,
    const float* __restrict__ att, const float* __restrict__ bias,
    const int* __restrict__ offsets, const int* __restrict__ csr_src,
    void* __restrict__ out0, int n, int mode)
{
    int wid = threadIdx.x >> 6;
    int node = (blockIdx.x << 2) + wid;
    if (node >= n) return;
    int lane = threadIdx.x & 63;
    int H = lane >> 5;
    int p = lane & 31;

    const half2v c02 = { (_Float16)0.2f, (_Float16)0.2f };

    half8 xrh = *(const half8*)(xr + (size_t)node * HIDHC + p * 8);
    half2v xr01 = __builtin_shufflevector(xrh, xrh, 0, 1);
    half2v xr23 = __builtin_shufflevector(xrh, xrh, 2, 3);
    half2v xr45 = __builtin_shufflevector(xrh, xrh, 4, 5);
    half2v xr67 = __builtin_shufflevector(xrh, xrh, 6, 7);

    float4 af0 = *(const float4*)(att + p * 8);
    float4 af1 = *(const float4*)(att + p * 8 + 4);
    half2v at01 = { (_Float16)af0.x, (_Float16)af0.y };
    half2v at23 = { (_Float16)af0.z, (_Float16)af0.w };
    half2v at45 = { (_Float16)af1.x, (_Float16)af1.y };
    half2v at67 = { (_Float16)af1.z, (_Float16)af1.w };

    float acc[8];
    #pragma unroll
    for (int k = 0; k < 8; ++k) acc[k] = 0.f;
    float d = 0.f;

    int j0 = __builtin_amdgcn_readfirstlane(offsets[node]);
    int j1 = __builtin_amdgcn_readfirstlane(offsets[node + 1]);
    int deg = j1 - j0;

    // --- fast path: adjacency row in one register (deg<=64) ---
    int fast = min(deg, 64);
    int npf = fast >> 1;                 // pairs handled by the pipeline
    int idxv = 0;
    if (lane < fast) idxv = csr_src[j0 + lane];

    half8 h0, h1;                        // depth-2 rotating gather pipeline
    if (npf > 0) {
        int s = __shfl(idxv, H, 64);
        h0 = *(const half8*)(xl + (size_t)s * HIDHC + p * 8);
    }
    if (npf > 1) {
        int s = __shfl(idxv, 2 + H, 64);
        h1 = *(const half8*)(xl + (size_t)s * HIDHC + p * 8);
    }
    for (int t = 0; t < npf; ++t) {
        half8 h = h0;
        h0 = h1;
        if (t + 2 < npf) {
            int s = __shfl(idxv, (t + 2) * 2 + H, 64);
            h1 = *(const half8*)(xl + (size_t)s * HIDHC + p * 8);
        }
        half2v h01 = __builtin_shufflevector(h, h, 0, 1);
        half2v h23 = __builtin_shufflevector(h, h, 2, 3);
        half2v h45 = __builtin_shufflevector(h, h, 4, 5);
        half2v h67 = __builtin_shufflevector(h, h, 6, 7);
        half2v s01 = h01 + xr01, s23 = h23 + xr23, s45 = h45 + xr45, s67 = h67 + xr67;
        half2v l01 = __builtin_elementwise_max(s01, s01 * c02);
        half2v l23 = __builtin_elementwise_max(s23, s23 * c02);
        half2v l45 = __builtin_elementwise_max(s45, s45 * c02);
        half2v l67 = __builtin_elementwise_max(s67, s67 * c02);
        float e = __builtin_amdgcn_fdot2(l01, at01, 0.f, false);
        e = __builtin_amdgcn_fdot2(l23, at23, e, false);
        e = __builtin_amdgcn_fdot2(l45, at45, e, false);
        e = __builtin_amdgcn_fdot2(l67, at67, e, false);
        e += __shfl_xor(e, 1);
        e += __shfl_xor(e, 2);
        e += __shfl_xor(e, 4);
        float pw = __expf(e);
        d += pw;
        #pragma unroll
        for (int k = 0; k < 8; ++k) acc[k] = fmaf(pw, (float)h[k], acc[k]);
    }

    // --- remainder: deg>64 pairs (rare) ---
    int j = j0 + (npf << 1);
    for (; j + 2 <= j1; j += 2) {
        int s0 = __builtin_amdgcn_readfirstlane(csr_src[j]);
        int s1 = __builtin_amdgcn_readfirstlane(csr_src[j + 1]);
        int s = H ? s1 : s0;
        half8 h = *(const half8*)(xl + (size_t)s * HIDHC + p * 8);
        half2v h01 = __builtin_shufflevector(h, h, 0, 1);
        half2v h23 = __builtin_shufflevector(h, h, 2, 3);
        half2v h45 = __builtin_shufflevector(h, h, 4, 5);
        half2v h67 = __builtin_shufflevector(h, h, 6, 7);
        half2v s01 = h01 + xr01, s23 = h23 + xr23, s45 = h45 + xr45, s67 = h67 + xr67;
        half2v l01 = __builtin_elementwise_max(s01, s01 * c02);
        half2v l23 = __builtin_elementwise_max(s23, s23 * c02);
        half2v l45 = __builtin_elementwise_max(s45, s45 * c02);
        half2v l67 = __builtin_elementwise_max(s67, s67 * c02);
        float e = __builtin_amdgcn_fdot2(l01, at01, 0.f, false);
        e = __builtin_amdgcn_fdot2(l23, at23, e, false);
        e = __builtin_amdgcn_fdot2(l45, at45, e, false);
        e = __builtin_amdgcn_fdot2(l67, at67, e, false);
        e += __shfl_xor(e, 1);
        e += __shfl_xor(e, 2);
        e += __shfl_xor(e, 4);
        float pw = __expf(e);
        d += pw;
        #pragma unroll
        for (int k = 0; k < 8; ++k) acc[k] = fmaf(pw, (float)h[k], acc[k]);
    }
    if (j < j1) {                        // odd leftover edge (H==0 half only)
        int s0 = __builtin_amdgcn_readfirstlane(csr_src[j]);
        half8 h = *(const half8*)(xl + (size_t)s0 * HIDHC + p * 8);
        half2v h01 = __builtin_shufflevector(h, h, 0, 1);
        half2v h23 = __builtin_shufflevector(h, h, 2, 3);
        half2v h45 = __builtin_shufflevector(h, h, 4, 5);
        half2v h67 = __builtin_shufflevector(h, h, 6, 7);
        half2v s01 = h01 + xr01, s23 = h23 + xr23, s45 = h45 + xr45, s67 = h67 + xr67;
        half2v l01 = __builtin_elementwise_max(s01, s01 * c02);
        half2v l23 = __builtin_elementwise_max(s23, s23 * c02);
        half2v l45 = __builtin_elementwise_max(s45, s45 * c02);
        half2v l67 = __builtin_elementwise_max(s67, s67 * c02);
        float e = __builtin_amdgcn_fdot2(l01, at01, 0.f, false);
        e = __builtin_amdgcn_fdot2(l23, at23, e, false);
        e = __builtin_amdgcn_fdot2(l45, at45, e, false);
        e = __builtin_amdgcn_fdot2(l67, at67, e, false);
        e += __shfl_xor(e, 1);
        e += __shfl_xor(e, 2);
        e += __shfl_xor(e, 4);
        float pw = (H == 0) ? __expf(e) : 0.f;
        d += pw;
        #pragma unroll
        for (int k = 0; k < 8; ++k) acc[k] = fmaf(pw, (float)h[k], acc[k]);
    }

    d += __shfl_xor(d, 32);
    #pragma unroll
    for (int k = 0; k < 8; ++k) acc[k] += __shfl_xor(acc[k], 32);

    float inv = 1.f / (d + 1e-16f);
    float o[8];
    #pragma unroll
    for (int k = 0; k < 8; ++k) o[k] = acc[k] * inv;

    if (mode == 0) {
        if (H == 0) {
            float4 b0 = *(const float4*)(bias + p * 8);
            float4 b1 = *(const float4*)(bias + p * 8 + 4);
            float bb[8] = { b0.x, b0.y, b0.z, b0.w, b1.x, b1.y, b1.z, b1.w };
            half8 hh;
            #pragma unroll
            for (int k = 0; k < 8; ++k) hh[k] = (_Float16)fmaxf(o[k] + bb[k], 0.f);
            *(half8*)((_Float16*)out0 + (size_t)node * HIDHC + p * 8) = hh;
        }
    } else {
        #pragma unroll
        for (int k = 0; k < 8; ++k) {
            o[k] += __shfl_xor(o[k], 8);
            o[k] += __shfl_xor(o[k], 16);
        }
        if (lane < 8) {
            float4 b0 = *(const float4*)(bias + p * 8);
            float4 b1 = *(const float4*)(bias + p * 8 + 4);
            float bb[8] = { b0.x, b0.y, b0.z, b0.w, b1.x, b1.y, b1.z, b1.w };
            float4 o0, o1;
            o0.x = fmaxf(o[0] * 0.25f + bb[0], 0.f);
            o0.y = fmaxf(o[1] * 0.25f + bb[1], 0.f);
            o0.z = fmaxf(o[2] * 0.25f + bb[2], 0.f);
            o0.w = fmaxf(o[3] * 0.25f + bb[3], 0.f);
            o1.x = fmaxf(o[4] * 0.25f + bb[4], 0.f);
            o1.y = fmaxf(o[5] * 0.25f + bb[5], 0.f);
            o1.z = fmaxf(o[6] * 0.25f + bb[6], 0.f);
            o1.w = fmaxf(o[7] * 0.25f + bb[7], 0.f);
            float* dst = (float*)out0 + (size_t)node * HID + p * 8;
            *(float4*)dst = o0;
            *(float4*)(dst + 4) = o1;
        }
    }
}

// -------------------- final linear: out[N,40] = h2[N,64] @ Wc[64,40] + bc --------------------

__global__ __launch_bounds__(256) void final_linear(
    const float* __restrict__ h2, const float* __restrict__ Wc,
    const float* __restrict__ bc, float* __restrict__ out, int n)
{
    __shared__ float Ws[HID * OUT_DIM];
    __shared__ float bs[OUT_DIM];
    __shared__ float hs[64][HID + 1];

    for (int i = threadIdx.x; i < HID * OUT_DIM; i += 256) Ws[i] = Wc[i];
    if (threadIdx.x < OUT_DIM) bs[threadIdx.x] = bc[threadIdx.x];

    int n0 = blockIdx.x * 64;
    for (int i = threadIdx.x; i < 64 * HID; i += 256) {
        int r = i >> 6, c = i & 63;
        int node = n0 + r;
        hs[r][c] = (node < n) ? h2[(size_t)node * HID + c] : 0.f;
    }
    __syncthreads();

    for (int idx = threadIdx.x; idx < 64 * OUT_DIM; idx += 256) {
        int r = idx / OUT_DIM, o = idx % OUT_DIM;
        int node = n0 + r;
        if (node < n) {
            float s = bs[o];
            #pragma unroll
            for (int c = 0; c < HID; ++c) s = fmaf(hs[r][c], Ws[c * OUT_DIM + o], s);
            out[(size_t)node * OUT_DIM + o] = s;
        }
    }
}

// -------------------- launch --------------------

extern "C" void kernel_launch(void* const* d_in, const int* in_sizes, int n_in,
                              void* d_out, int out_size, void* d_ws, size_t ws_size,
                              hipStream_t stream) {
    const int N = in_sizes[0] / IN_DIM;   // 50000
    const int E = in_sizes[1];            // 800000

    const float* x    = (const float*)d_in[0];
    const int*   src  = (const int*)d_in[1];
    const int*   dst  = (const int*)d_in[2];
    const float* Wl1  = (const float*)d_in[3];
    const float* bl1  = (const float*)d_in[4];
    const float* Wr1  = (const float*)d_in[5];
    const float* br1  = (const float*)d_in[6];
    const float* att1 = (const float*)d_in[7];
    const float* bias1= (const float*)d_in[8];
    const float* Wl2  = (const float*)d_in[9];
    const float* bl2  = (const float*)d_in[10];
    const float* Wr2  = (const float*)d_in[11];
    const float* br2  = (const float*)d_in[12];
    const float* att2 = (const float*)d_in[13];
    const float* bias2= (const float*)d_in[14];
    const float* Wc   = (const float*)d_in[15];
    const float* bc   = (const float*)d_in[16];

    char* ws = (char*)d_ws;
    size_t off = 0;
    _Float16* xlh = (_Float16*)(ws + off); off += (size_t)N * HIDHC * 2;  // xl fp16
    _Float16* xrh = (_Float16*)(ws + off); off += (size_t)N * HIDHC * 2;  // xr fp16
    _Float16* Af  = (_Float16*)(ws + off); off += (size_t)N * HIDHC * 2;  // x / h1 fp16
    float*    h2  = (float*)(ws + off);    off += (size_t)N * HID * 4;
    _Float16* Wt  = (_Float16*)(ws + off); off += (size_t)4 * 65536 * 2;
    int* deg     = (int*)(ws + off); off += (size_t)N * 4;
    int* offsets = (int*)(ws + off); off += (size_t)(N + 1) * 4;
    int* cursor  = (int*)(ws + off); off += (size_t)N * 4;
    int* csr     = (int*)(ws + off); off += (size_t)E * 4;
    int* bsum    = (int*)(ws + off); off += 256 * 4;
    int* bpre    = (int*)(ws + off); off += 256 * 4;

    const int NB = (N + 255) / 256;

    // CSR build (parallel scan) + input prep
    hipMemsetAsync(deg, 0, (size_t)N * 4, stream);
    edge_hist<<<(E + 255) / 256, 256, 0, stream>>>(dst, deg, E);
    deg_block_reduce<<<NB, 256, 0, stream>>>(deg, bsum, N);
    scan_bsums<<<1, 256, 0, stream>>>(bsum, bpre, NB);
    deg_scan_apply<<<NB, 256, 0, stream>>>(deg, bpre, offsets, cursor, N);
    edge_scatter<<<(E + 255) / 256, 256, 0, stream>>>(src, dst, cursor, csr, E);
    prep_weights<<<dim3(256, 4), 256, 0, stream>>>(Wl1, Wr1, Wl2, Wr2, Wt);
    cvt_f16<<<(N * HIDHC / 4 + 255) / 256, 256, 0, stream>>>(x, Af, N * HIDHC / 4);

    const int KW = 65536;
    dim3 gg((N + 127) / 128, 2, 2);
    // layer 1
    gemm2_mfma<<<gg, 256, 0, stream>>>(Af,
        Wt + 0 * KW, bl1, xlh,
        Wt + 1 * KW, br1, xrh, N);
    gat_node<<<(N + 3) / 4, 256, 0, stream>>>(xlh, xrh, att1, bias1, offsets, csr,
                                              (void*)Af, N, 0);
    // layer 2
    gemm2_mfma<<<gg, 256, 0, stream>>>(Af,
        Wt + 2 * KW, bl2, xlh,
        Wt + 3 * KW, br2, xrh, N);
    gat_node<<<(N + 3) / 4, 256, 0, stream>>>(xlh, xrh, att2, bias2, offsets, csr,
                                              (void*)h2, N, 1);
    // head
    final_linear<<<(N + 63) / 64, 256, 0, stream>>>(h2, Wc, bc, (float*)d_out, N);
}

// Round 4
// 445.160 us; speedup vs baseline: 1.0476x; 1.0437x over previous
//
#include <hip/hip_runtime.h>
#include <hip/hip_bf16.h>
#include <math.h>

// ---------------------------------------------------------------------------
// GATv2 2-layer + linear head, MI355X (gfx950)
// gemm_dual: ONE block computes the (bm,bn) tile for BOTH weight matrices
//   (Wl and Wr). 8 waves/block (512 thr): waves 0-3 -> z=0, waves 4-7 -> z=1;
//   A-tile staged ONCE per K-step and shared, W0+W1 staged side-by-side.
//   Halves A traffic and doubles MFMA work per barrier drain.
// gat_node: round-2 structure + depth-4 rotating gather pipeline (falsifying
//   test of the miss-queue-bound model: if flat, gather is at its floor).
// CSR build: parallel 3-phase scan (unchanged).
// (Resubmission of round 3 — container infra failure, no counters returned.)
// ---------------------------------------------------------------------------

#define IN_DIM 256
#define HIDHC 256   // HEADS*HID
#define HID 64
#define OUT_DIM 40

using half8  = __attribute__((ext_vector_type(8))) _Float16;
using half4  = __attribute__((ext_vector_type(4))) _Float16;
using half2v = __attribute__((ext_vector_type(2))) _Float16;
using f32x4  = __attribute__((ext_vector_type(4))) float;

__device__ __forceinline__ void gload16(const void* g, void* l) {
    __builtin_amdgcn_global_load_lds(
        (const __attribute__((address_space(1))) void*)g,
        (__attribute__((address_space(3))) void*)l, 16, 0, 0);
}

// -------------------- CSR build --------------------

__global__ void edge_hist(const int* __restrict__ dst, int* __restrict__ deg, int E) {
    int i = blockIdx.x * blockDim.x + threadIdx.x;
    if (i < E) atomicAdd(&deg[dst[i]], 1);
}

__global__ void deg_block_reduce(const int* __restrict__ deg, int* __restrict__ bsum, int n) {
    int i = blockIdx.x * 256 + threadIdx.x;
    int v = (i < n) ? deg[i] : 0;
    #pragma unroll
    for (int off = 32; off; off >>= 1) v += __shfl_xor(v, off, 64);
    __shared__ int ws[4];
    int lane = threadIdx.x & 63, wid = threadIdx.x >> 6;
    if (lane == 0) ws[wid] = v;
    __syncthreads();
    if (threadIdx.x == 0) bsum[blockIdx.x] = ws[0] + ws[1] + ws[2] + ws[3];
}

__global__ void scan_bsums(const int* __restrict__ bsum, int* __restrict__ bpre, int nb) {
    __shared__ int s[256];
    int tid = threadIdx.x;
    int orig = (tid < nb) ? bsum[tid] : 0;
    s[tid] = orig;
    __syncthreads();
    #pragma unroll
    for (int off = 1; off < 256; off <<= 1) {
        int t = (tid >= off) ? s[tid - off] : 0;
        __syncthreads();
        s[tid] += t;
        __syncthreads();
    }
    if (tid < nb) bpre[tid] = s[tid] - orig;
}

__global__ void deg_scan_apply(const int* __restrict__ deg, const int* __restrict__ bpre,
                               int* __restrict__ offsets, int* __restrict__ cursor, int n) {
    int i = blockIdx.x * 256 + threadIdx.x;
    int lane = threadIdx.x & 63, wid = threadIdx.x >> 6;
    int v = (i < n) ? deg[i] : 0;
    int inc = v;
    #pragma unroll
    for (int off = 1; off < 64; off <<= 1) {
        int t = __shfl_up(inc, off, 64);
        if (lane >= off) inc += t;
    }
    __shared__ int ws[4];
    if (lane == 63) ws[wid] = inc;
    __syncthreads();
    int add = bpre[blockIdx.x];
    for (int w = 0; w < wid; ++w) add += ws[w];
    int incl = inc + add;
    if (i < n) { offsets[i + 1] = incl; cursor[i] = incl - v; }
    if (i == 0) offsets[0] = 0;
}

__global__ void edge_scatter(const int* __restrict__ src, const int* __restrict__ dst,
                             int* __restrict__ cursor, int* __restrict__ csr_src, int E) {
    int i = blockIdx.x * blockDim.x + threadIdx.x;
    if (i < E) {
        int p = atomicAdd(&cursor[dst[i]], 1);
        csr_src[p] = src[i];
    }
}

// -------------------- input prep --------------------

__global__ void cvt_f16(const float* __restrict__ in, _Float16* __restrict__ out, int n4) {
    int i = blockIdx.x * blockDim.x + threadIdx.x;
    if (i >= n4) return;
    float4 v = ((const float4*)in)[i];
    half4 h = { (_Float16)v.x, (_Float16)v.y, (_Float16)v.z, (_Float16)v.w };
    ((half4*)out)[i] = h;
}

// W [256][256] fp32 (k-major) -> per weight: [n][k] fp16 (transposed)
__global__ void prep_weights(const float* __restrict__ W0, const float* __restrict__ W1,
                             const float* __restrict__ W2, const float* __restrict__ W3,
                             _Float16* __restrict__ T) {
    const float* Wsel = (blockIdx.y == 0) ? W0 : (blockIdx.y == 1) ? W1
                      : (blockIdx.y == 2) ? W2 : W3;
    int k = blockIdx.x, nn = threadIdx.x;
    float v = Wsel[k * 256 + nn];
    T[(size_t)blockIdx.y * 65536 + (size_t)nn * 256 + k] = (_Float16)v;
}

// -------------------- dual MFMA GEMM: xl and xr in one block --------------------
// C0[M,256] = A@W0 + b0, C1[M,256] = A@W1 + b1, fp16 in/out, fp32 accum.
// 128x128 tile, BK=32 (8 iters), 8 waves: z = w>>2 picks (W,bias,C).
// A staged once per K-step (shared by all 8 waves); W0,W1 staged adjacent.
// LDS ping-pong via global_load_lds; full waitcnt drain before each barrier.

__global__ __launch_bounds__(512) void gemm_dual(
    const _Float16* __restrict__ A,
    const _Float16* __restrict__ W0, const float* __restrict__ b0, _Float16* __restrict__ C0,
    const _Float16* __restrict__ W1, const float* __restrict__ b1, _Float16* __restrict__ C1,
    int M)
{
    __shared__ __align__(16) _Float16 sA[2][4096];        // 128x32 per buf
    __shared__ __align__(16) _Float16 sW[2][2][4096];     // [buf][z][128x32]

    int tid = threadIdx.x;
    int bm = blockIdx.x * 128;
    int bn = blockIdx.y * 128;

    int lane = tid & 63, w = tid >> 6;       // 8 waves
    int z  = w >> 2, wq = w & 3;
    int r = lane & 15, q = lane >> 4;
    int m0 = (wq >> 1) * 64, n0 = (wq & 1) * 64;

    // one granule per thread per array: g = tid; kg = g>>7 (0..3), row = g&127
    int g = tid;
    int kgo = (g >> 7) * 8;
    int row = g & 127;
    int arow = min(bm + row, M - 1);
    int brow = bn + row;
    int ldso = g * 8;

    f32x4 acc[4][4];
    #pragma unroll
    for (int i = 0; i < 4; ++i)
        #pragma unroll
        for (int j = 0; j < 4; ++j) acc[i][j] = (f32x4)0.f;

    // preload tile 0 into buffer 0
    gload16(A  + (size_t)arow * 256 + kgo, &sA[0][ldso]);
    gload16(W0 + (size_t)brow * 256 + kgo, &sW[0][0][ldso]);
    gload16(W1 + (size_t)brow * 256 + kgo, &sW[0][1][ldso]);
    __builtin_amdgcn_s_waitcnt(0);   // drain LDS-DMA
    __syncthreads();

    #pragma unroll 1
    for (int kt = 0; kt < 8; ++kt) {
        int buf = kt & 1;
        if (kt < 7) {
            int k0 = (kt + 1) * 32;
            gload16(A  + (size_t)arow * 256 + k0 + kgo, &sA[buf ^ 1][ldso]);
            gload16(W0 + (size_t)brow * 256 + k0 + kgo, &sW[buf ^ 1][0][ldso]);
            gload16(W1 + (size_t)brow * 256 + k0 + kgo, &sW[buf ^ 1][1][ldso]);
        }
        half8 a[4], b[4];
        #pragma unroll
        for (int i = 0; i < 4; ++i) {
            a[i] = *(const half8*)(&sA[buf][(q * 128 + m0 + i * 16 + r) * 8]);
            b[i] = *(const half8*)(&sW[buf][z][(q * 128 + n0 + i * 16 + r) * 8]);
        }
        #pragma unroll
        for (int i = 0; i < 4; ++i)
            #pragma unroll
            for (int j = 0; j < 4; ++j)
                acc[i][j] = __builtin_amdgcn_mfma_f32_16x16x32_f16(a[i], b[j], acc[i][j], 0, 0, 0);
        __builtin_amdgcn_s_waitcnt(0);   // drain prefetch DMA before buffer swap
        __syncthreads();
    }

    const float* bias = z ? b1 : b0;
    _Float16*    C    = z ? C1 : C0;

    // epilogue: C/D layout col=lane&15, row=q*4+reg
    float bv[4];
    #pragma unroll
    for (int j = 0; j < 4; ++j) bv[j] = bias[bn + n0 + j * 16 + r];
    #pragma unroll
    for (int i = 0; i < 4; ++i) {
        #pragma unroll
        for (int reg = 0; reg < 4; ++reg) {
            int orow = bm + m0 + i * 16 + q * 4 + reg;
            if (orow < M) {
                #pragma unroll
                for (int j = 0; j < 4; ++j)
                    C[(size_t)orow * 256 + bn + n0 + j * 16 + r] =
                        (_Float16)(acc[i][j][reg] + bv[j]);
            }
        }
    }
}

// -------------------- GAT node kernel: half-wave-per-edge ---------------------
// 1 node/wave, 12500 blocks (dynamic balancing). Adjacency row preloaded into
// idxv (1 coalesced load, deg<=64); per-pair src via __shfl; depth-4 rotating
// gather pipeline keeps four 512B xl rows in flight. deg>64 -> scalar fallback.

__global__ __launch_bounds__(256) void gat_node(
    const _Float16* __restrict__ xl, const _Float16* __restrict__ xr,
    const float* __restrict__ att, const float* __restrict__ bias,
    const int* __restrict__ offsets, const int* __restrict__ csr_src,
    void* __restrict__ out0, int n, int mode)
{
    int wid = threadIdx.x >> 6;
    int node = (blockIdx.x << 2) + wid;
    if (node >= n) return;
    int lane = threadIdx.x & 63;
    int H = lane >> 5;
    int p = lane & 31;

    const half2v c02 = { (_Float16)0.2f, (_Float16)0.2f };

    half8 xrh = *(const half8*)(xr + (size_t)node * HIDHC + p * 8);
    half2v xr01 = __builtin_shufflevector(xrh, xrh, 0, 1);
    half2v xr23 = __builtin_shufflevector(xrh, xrh, 2, 3);
    half2v xr45 = __builtin_shufflevector(xrh, xrh, 4, 5);
    half2v xr67 = __builtin_shufflevector(xrh, xrh, 6, 7);

    float4 af0 = *(const float4*)(att + p * 8);
    float4 af1 = *(const float4*)(att + p * 8 + 4);
    half2v at01 = { (_Float16)af0.x, (_Float16)af0.y };
    half2v at23 = { (_Float16)af0.z, (_Float16)af0.w };
    half2v at45 = { (_Float16)af1.x, (_Float16)af1.y };
    half2v at67 = { (_Float16)af1.z, (_Float16)af1.w };

    float acc[8];
    #pragma unroll
    for (int k = 0; k < 8; ++k) acc[k] = 0.f;
    float d = 0.f;

    int j0 = __builtin_amdgcn_readfirstlane(offsets[node]);
    int j1 = __builtin_amdgcn_readfirstlane(offsets[node + 1]);
    int deg = j1 - j0;

    // --- fast path: adjacency row in one register (deg<=64) ---
    int fast = min(deg, 64);
    int npf = fast >> 1;                 // pairs handled by the pipeline
    int idxv = 0;
    if (lane < fast) idxv = csr_src[j0 + lane];

    half8 hb0, hb1, hb2, hb3;            // depth-4 rotating gather pipeline
    if (npf > 0) { int s = __shfl(idxv, 0 + H, 64); hb0 = *(const half8*)(xl + (size_t)s * HIDHC + p * 8); }
    if (npf > 1) { int s = __shfl(idxv, 2 + H, 64); hb1 = *(const half8*)(xl + (size_t)s * HIDHC + p * 8); }
    if (npf > 2) { int s = __shfl(idxv, 4 + H, 64); hb2 = *(const half8*)(xl + (size_t)s * HIDHC + p * 8); }
    if (npf > 3) { int s = __shfl(idxv, 6 + H, 64); hb3 = *(const half8*)(xl + (size_t)s * HIDHC + p * 8); }
    for (int t = 0; t < npf; ++t) {
        half8 h = hb0;
        hb0 = hb1; hb1 = hb2; hb2 = hb3;
        if (t + 4 < npf) {
            int s = __shfl(idxv, (t + 4) * 2 + H, 64);
            hb3 = *(const half8*)(xl + (size_t)s * HIDHC + p * 8);
        }
        half2v h01 = __builtin_shufflevector(h, h, 0, 1);
        half2v h23 = __builtin_shufflevector(h, h, 2, 3);
        half2v h45 = __builtin_shufflevector(h, h, 4, 5);
        half2v h67 = __builtin_shufflevector(h, h, 6, 7);
        half2v s01 = h01 + xr01, s23 = h23 + xr23, s45 = h45 + xr45, s67 = h67 + xr67;
        half2v l01 = __builtin_elementwise_max(s01, s01 * c02);
        half2v l23 = __builtin_elementwise_max(s23, s23 * c02);
        half2v l45 = __builtin_elementwise_max(s45, s45 * c02);
        half2v l67 = __builtin_elementwise_max(s67, s67 * c02);
        float e = __builtin_amdgcn_fdot2(l01, at01, 0.f, false);
        e = __builtin_amdgcn_fdot2(l23, at23, e, false);
        e = __builtin_amdgcn_fdot2(l45, at45, e, false);
        e = __builtin_amdgcn_fdot2(l67, at67, e, false);
        e += __shfl_xor(e, 1);
        e += __shfl_xor(e, 2);
        e += __shfl_xor(e, 4);
        float pw = __expf(e);
        d += pw;
        #pragma unroll
        for (int k = 0; k < 8; ++k) acc[k] = fmaf(pw, (float)h[k], acc[k]);
    }

    // --- remainder: deg>64 pairs (rare) ---
    int j = j0 + (npf << 1);
    for (; j + 2 <= j1; j += 2) {
        int s0 = __builtin_amdgcn_readfirstlane(csr_src[j]);
        int s1 = __builtin_amdgcn_readfirstlane(csr_src[j + 1]);
        int s = H ? s1 : s0;
        half8 h = *(const half8*)(xl + (size_t)s * HIDHC + p * 8);
        half2v h01 = __builtin_shufflevector(h, h, 0, 1);
        half2v h23 = __builtin_shufflevector(h, h, 2, 3);
        half2v h45 = __builtin_shufflevector(h, h, 4, 5);
        half2v h67 = __builtin_shufflevector(h, h, 6, 7);
        half2v s01 = h01 + xr01, s23 = h23 + xr23, s45 = h45 + xr45, s67 = h67 + xr67;
        half2v l01 = __builtin_elementwise_max(s01, s01 * c02);
        half2v l23 = __builtin_elementwise_max(s23, s23 * c02);
        half2v l45 = __builtin_elementwise_max(s45, s45 * c02);
        half2v l67 = __builtin_elementwise_max(s67, s67 * c02);
        float e = __builtin_amdgcn_fdot2(l01, at01, 0.f, false);
        e = __builtin_amdgcn_fdot2(l23, at23, e, false);
        e = __builtin_amdgcn_fdot2(l45, at45, e, false);
        e = __builtin_amdgcn_fdot2(l67, at67, e, false);
        e += __shfl_xor(e, 1);
        e += __shfl_xor(e, 2);
        e += __shfl_xor(e, 4);
        float pw = __expf(e);
        d += pw;
        #pragma unroll
        for (int k = 0; k < 8; ++k) acc[k] = fmaf(pw, (float)h[k], acc[k]);
    }
    if (j < j1) {                        // odd leftover edge (H==0 half only)
        int s0 = __builtin_amdgcn_readfirstlane(csr_src[j]);
        half8 h = *(const half8*)(xl + (size_t)s0 * HIDHC + p * 8);
        half2v h01 = __builtin_shufflevector(h, h, 0, 1);
        half2v h23 = __builtin_shufflevector(h, h, 2, 3);
        half2v h45 = __builtin_shufflevector(h, h, 4, 5);
        half2v h67 = __builtin_shufflevector(h, h, 6, 7);
        half2v s01 = h01 + xr01, s23 = h23 + xr23, s45 = h45 + xr45, s67 = h67 + xr67;
        half2v l01 = __builtin_elementwise_max(s01, s01 * c02);
        half2v l23 = __builtin_elementwise_max(s23, s23 * c02);
        half2v l45 = __builtin_elementwise_max(s45, s45 * c02);
        half2v l67 = __builtin_elementwise_max(s67, s67 * c02);
        float e = __builtin_amdgcn_fdot2(l01, at01, 0.f, false);
        e = __builtin_amdgcn_fdot2(l23, at23, e, false);
        e = __builtin_amdgcn_fdot2(l45, at45, e, false);
        e = __builtin_amdgcn_fdot2(l67, at67, e, false);
        e += __shfl_xor(e, 1);
        e += __shfl_xor(e, 2);
        e += __shfl_xor(e, 4);
        float pw = (H == 0) ? __expf(e) : 0.f;
        d += pw;
        #pragma unroll
        for (int k = 0; k < 8; ++k) acc[k] = fmaf(pw, (float)h[k], acc[k]);
    }

    d += __shfl_xor(d, 32);
    #pragma unroll
    for (int k = 0; k < 8; ++k) acc[k] += __shfl_xor(acc[k], 32);

    float inv = 1.f / (d + 1e-16f);
    float o[8];
    #pragma unroll
    for (int k = 0; k < 8; ++k) o[k] = acc[k] * inv;

    if (mode == 0) {
        if (H == 0) {
            float4 b0 = *(const float4*)(bias + p * 8);
            float4 b1 = *(const float4*)(bias + p * 8 + 4);
            float bb[8] = { b0.x, b0.y, b0.z, b0.w, b1.x, b1.y, b1.z, b1.w };
            half8 hh;
            #pragma unroll
            for (int k = 0; k < 8; ++k) hh[k] = (_Float16)fmaxf(o[k] + bb[k], 0.f);
            *(half8*)((_Float16*)out0 + (size_t)node * HIDHC + p * 8) = hh;
        }
    } else {
        #pragma unroll
        for (int k = 0; k < 8; ++k) {
            o[k] += __shfl_xor(o[k], 8);
            o[k] += __shfl_xor(o[k], 16);
        }
        if (lane < 8) {
            float4 b0 = *(const float4*)(bias + p * 8);
            float4 b1 = *(const float4*)(bias + p * 8 + 4);
            float bb[8] = { b0.x, b0.y, b0.z, b0.w, b1.x, b1.y, b1.z, b1.w };
            float4 o0, o1;
            o0.x = fmaxf(o[0] * 0.25f + bb[0], 0.f);
            o0.y = fmaxf(o[1] * 0.25f + bb[1], 0.f);
            o0.z = fmaxf(o[2] * 0.25f + bb[2], 0.f);
            o0.w = fmaxf(o[3] * 0.25f + bb[3], 0.f);
            o1.x = fmaxf(o[4] * 0.25f + bb[4], 0.f);
            o1.y = fmaxf(o[5] * 0.25f + bb[5], 0.f);
            o1.z = fmaxf(o[6] * 0.25f + bb[6], 0.f);
            o1.w = fmaxf(o[7] * 0.25f + bb[7], 0.f);
            float* dst = (float*)out0 + (size_t)node * HID + p * 8;
            *(float4*)dst = o0;
            *(float4*)(dst + 4) = o1;
        }
    }
}

// -------------------- final linear: out[N,40] = h2[N,64] @ Wc[64,40] + bc --------------------

__global__ __launch_bounds__(256) void final_linear(
    const float* __restrict__ h2, const float* __restrict__ Wc,
    const float* __restrict__ bc, float* __restrict__ out, int n)
{
    __shared__ float Ws[HID * OUT_DIM];
    __shared__ float bs[OUT_DIM];
    __shared__ float hs[64][HID + 1];

    for (int i = threadIdx.x; i < HID * OUT_DIM; i += 256) Ws[i] = Wc[i];
    if (threadIdx.x < OUT_DIM) bs[threadIdx.x] = bc[threadIdx.x];

    int n0 = blockIdx.x * 64;
    for (int i = threadIdx.x; i < 64 * HID; i += 256) {
        int r = i >> 6, c = i & 63;
        int node = n0 + r;
        hs[r][c] = (node < n) ? h2[(size_t)node * HID + c] : 0.f;
    }
    __syncthreads();

    for (int idx = threadIdx.x; idx < 64 * OUT_DIM; idx += 256) {
        int r = idx / OUT_DIM, o = idx % OUT_DIM;
        int node = n0 + r;
        if (node < n) {
            float s = bs[o];
            #pragma unroll
            for (int c = 0; c < HID; ++c) s = fmaf(hs[r][c], Ws[c * OUT_DIM + o], s);
            out[(size_t)node * OUT_DIM + o] = s;
        }
    }
}

// -------------------- launch --------------------

extern "C" void kernel_launch(void* const* d_in, const int* in_sizes, int n_in,
                              void* d_out, int out_size, void* d_ws, size_t ws_size,
                              hipStream_t stream) {
    const int N = in_sizes[0] / IN_DIM;   // 50000
    const int E = in_sizes[1];            // 800000

    const float* x    = (const float*)d_in[0];
    const int*   src  = (const int*)d_in[1];
    const int*   dst  = (const int*)d_in[2];
    const float* Wl1  = (const float*)d_in[3];
    const float* bl1  = (const float*)d_in[4];
    const float* Wr1  = (const float*)d_in[5];
    const float* br1  = (const float*)d_in[6];
    const float* att1 = (const float*)d_in[7];
    const float* bias1= (const float*)d_in[8];
    const float* Wl2  = (const float*)d_in[9];
    const float* bl2  = (const float*)d_in[10];
    const float* Wr2  = (const float*)d_in[11];
    const float* br2  = (const float*)d_in[12];
    const float* att2 = (const float*)d_in[13];
    const float* bias2= (const float*)d_in[14];
    const float* Wc   = (const float*)d_in[15];
    const float* bc   = (const float*)d_in[16];

    char* ws = (char*)d_ws;
    size_t off = 0;
    _Float16* xlh = (_Float16*)(ws + off); off += (size_t)N * HIDHC * 2;  // xl fp16
    _Float16* xrh = (_Float16*)(ws + off); off += (size_t)N * HIDHC * 2;  // xr fp16
    _Float16* Af  = (_Float16*)(ws + off); off += (size_t)N * HIDHC * 2;  // x / h1 fp16
    float*    h2  = (float*)(ws + off);    off += (size_t)N * HID * 4;
    _Float16* Wt  = (_Float16*)(ws + off); off += (size_t)4 * 65536 * 2;
    int* deg     = (int*)(ws + off); off += (size_t)N * 4;
    int* offsets = (int*)(ws + off); off += (size_t)(N + 1) * 4;
    int* cursor  = (int*)(ws + off); off += (size_t)N * 4;
    int* csr     = (int*)(ws + off); off += (size_t)E * 4;
    int* bsum    = (int*)(ws + off); off += 256 * 4;
    int* bpre    = (int*)(ws + off); off += 256 * 4;

    const int NB = (N + 255) / 256;

    // CSR build (parallel scan) + input prep
    hipMemsetAsync(deg, 0, (size_t)N * 4, stream);
    edge_hist<<<(E + 255) / 256, 256, 0, stream>>>(dst, deg, E);
    deg_block_reduce<<<NB, 256, 0, stream>>>(deg, bsum, N);
    scan_bsums<<<1, 256, 0, stream>>>(bsum, bpre, NB);
    deg_scan_apply<<<NB, 256, 0, stream>>>(deg, bpre, offsets, cursor, N);
    edge_scatter<<<(E + 255) / 256, 256, 0, stream>>>(src, dst, cursor, csr, E);
    prep_weights<<<dim3(256, 4), 256, 0, stream>>>(Wl1, Wr1, Wl2, Wr2, Wt);
    cvt_f16<<<(N * HIDHC / 4 + 255) / 256, 256, 0, stream>>>(x, Af, N * HIDHC / 4);

    const int KW = 65536;
    dim3 gg((N + 127) / 128, 2);
    // layer 1
    gemm_dual<<<gg, 512, 0, stream>>>(Af,
        Wt + 0 * KW, bl1, xlh,
        Wt + 1 * KW, br1, xrh, N);
    gat_node<<<(N + 3) / 4, 256, 0, stream>>>(xlh, xrh, att1, bias1, offsets, csr,
                                              (void*)Af, N, 0);
    // layer 2
    gemm_dual<<<gg, 512, 0, stream>>>(Af,
        Wt + 2 * KW, bl2, xlh,
        Wt + 3 * KW, br2, xrh, N);
    gat_node<<<(N + 3) / 4, 256, 0, stream>>>(xlh, xrh, att2, bias2, offsets, csr,
                                              (void*)h2, N, 1);
    // head
    final_linear<<<(N + 63) / 64, 256, 0, stream>>>(h2, Wc, bc, (float*)d_out, N);
}